// Round 1
// baseline (378.487 us; speedup 1.0000x reference)
//
#include <hip/hip_runtime.h>
#include <stdint.h>

#define N_TOK 8192
#define C_DIM 768
#define E_NUM 8

typedef short short8 __attribute__((ext_vector_type(8)));
typedef __bf16 bf16x8 __attribute__((ext_vector_type(8)));
typedef float f32x4 __attribute__((ext_vector_type(4)));

static __device__ __forceinline__ unsigned short f2bf(float f) {
    unsigned u = __float_as_uint(f);
    unsigned r = u + 0x7FFFu + ((u >> 16) & 1u);
    return (unsigned short)(r >> 16);
}
static __device__ __forceinline__ float bf2f(unsigned short h) {
    return __uint_as_float(((unsigned)h) << 16);
}

// ---------------- convert x: fp32 -> bf16 ----------------
__global__ void convert_x_kernel(const float* __restrict__ x, unsigned short* __restrict__ xb, int n4) {
    int i = blockIdx.x * blockDim.x + threadIdx.x;
    if (i >= n4) return;
    const float4 v = *reinterpret_cast<const float4*>(x + (size_t)i * 4);
    ushort4 o;
    o.x = f2bf(v.x); o.y = f2bf(v.y); o.z = f2bf(v.z); o.w = f2bf(v.w);
    *reinterpret_cast<ushort4*>(xb + (size_t)i * 4) = o;
}

// ------------- transpose+convert weights: Wt[m][o][i] = W[m][i][o], bf16 -------------
// m: 0=w_fc_sh, 1=w_proj_sh, 2..9=w1[e], 10..17=w2[e]
__global__ void wtrans_kernel(const float* __restrict__ wfc, const float* __restrict__ wpj,
                              const float* __restrict__ w1, const float* __restrict__ w2,
                              unsigned short* __restrict__ Wt) {
    __shared__ float tile[32][33];
    const int m = blockIdx.z;
    const float* src = (m == 0) ? wfc : (m == 1) ? wpj
                     : (m < 10) ? (w1 + (size_t)(m - 2) * C_DIM * C_DIM)
                                : (w2 + (size_t)(m - 10) * C_DIM * C_DIM);
    const int i0 = blockIdx.y * 32;   // input-dim block
    const int o0 = blockIdx.x * 32;   // output-dim block
    #pragma unroll
    for (int rr = 0; rr < 32; rr += 8)
        tile[threadIdx.y + rr][threadIdx.x] = src[(size_t)(i0 + threadIdx.y + rr) * C_DIM + o0 + threadIdx.x];
    __syncthreads();
    unsigned short* dst = Wt + (size_t)m * C_DIM * C_DIM;
    #pragma unroll
    for (int rr = 0; rr < 32; rr += 8) {
        int o = o0 + threadIdx.y + rr;
        dst[(size_t)o * C_DIM + i0 + threadIdx.x] = f2bf(tile[threadIdx.x][threadIdx.y + rr]);
    }
}

// ---------------- router: fp32 logits, sigmoid, top-2, buckets ----------------
__global__ void router_kernel(const float* __restrict__ x, const float* __restrict__ rw,
                              const float* __restrict__ bias,
                              float* __restrict__ topk_w,
                              int* __restrict__ counts, int* __restrict__ buckets) {
    const int wave = threadIdx.x >> 6;
    const int lane = threadIdx.x & 63;
    const int n = blockIdx.x * 4 + wave;
    const float* xp = x + (size_t)n * C_DIM + lane * 12;
    float xv[12];
    #pragma unroll
    for (int j = 0; j < 12; j++) xv[j] = xp[j];
    float acc[E_NUM];
    #pragma unroll
    for (int e = 0; e < E_NUM; e++) acc[e] = 0.f;
    #pragma unroll
    for (int e = 0; e < E_NUM; e++) {
        const float* wp = rw + (size_t)e * C_DIM + lane * 12;
        #pragma unroll
        for (int j = 0; j < 12; j++) acc[e] += xv[j] * wp[j];
    }
    #pragma unroll
    for (int e = 0; e < E_NUM; e++) {
        #pragma unroll
        for (int off = 32; off > 0; off >>= 1) acc[e] += __shfl_xor(acc[e], off, 64);
    }
    if (lane == 0) {
        float sc[E_NUM];
        #pragma unroll
        for (int e = 0; e < E_NUM; e++) sc[e] = 1.f / (1.f + expf(-acc[e]));
        int e0 = 0; float best = -1e30f;
        #pragma unroll
        for (int e = 0; e < E_NUM; e++) { float v = sc[e] + bias[e]; if (v > best) { best = v; e0 = e; } }
        int e1 = -1; float best1 = -1e30f;
        #pragma unroll
        for (int e = 0; e < E_NUM; e++) { if (e == e0) continue; float v = sc[e] + bias[e]; if (v > best1) { best1 = v; e1 = e; } }
        float w0 = sc[e0], w1 = sc[e1];
        float s = w0 + w1 + 1e-20f;
        w0 /= s; w1 /= s;
        topk_w[n * 2] = w0; topk_w[n * 2 + 1] = w1;
        int p0 = atomicAdd(&counts[e0], 1); buckets[e0 * N_TOK + p0] = n * 2;
        int p1 = atomicAdd(&counts[e1], 1); buckets[e1 * N_TOK + p1] = n * 2 + 1;
    }
}

// ---------------- bf16 MFMA GEMM, 128x128 tile, BK=32, 4 waves ----------------
// MODE 0: shared fc:   A=xb rows direct,   epi relu^2 -> H[n]        (bf16)
// MODE 1: shared proj: A=H rows direct,    epi write  -> out[n]      (fp32)
// MODE 2: expert fc:   A=xb gathered,      epi relu^2 -> H[entry]    (bf16)
// MODE 3: expert proj: A=H gathered,       epi write  -> Y[entry]    (bf16)
#define GLOAD_LDS(g, l) __builtin_amdgcn_global_load_lds((const __attribute__((address_space(1))) void*)(g), (__attribute__((address_space(3))) void*)(l), 16, 0, 0)

template <int MODE>
__global__ __launch_bounds__(256) void gemm_kernel(const unsigned short* __restrict__ Asrc,
                                                   const unsigned short* __restrict__ WtAll,
                                                   void* __restrict__ dst,
                                                   const int* __restrict__ counts,
                                                   const int* __restrict__ buckets) {
    const int e = (MODE >= 2) ? blockIdx.z : 0;
    int rows;
    if constexpr (MODE < 2) rows = N_TOK; else rows = counts[e];
    const int r0 = blockIdx.x * 128;
    if (r0 >= rows) return;
    const int c0 = blockIdx.y * 128;

    __shared__ __align__(16) unsigned short As[128 * 32];
    __shared__ __align__(16) unsigned short Bs[128 * 32];

    const int t = threadIdx.x;
    const int lane = t & 63;
    const int wv = t >> 6;
    const int wr = (wv >> 1) * 64;
    const int wc = (wv & 1) * 64;

    const int widx = (MODE == 0) ? 0 : (MODE == 1) ? 1 : (MODE == 2) ? (2 + e) : (10 + e);
    const unsigned short* Bmat = WtAll + (size_t)widx * C_DIM * C_DIM;

    // staging row map (2 rows per thread per tile)
    const int ar0 = t >> 2;
    const int ar1 = 64 + (t >> 2);
    const int acol = (t & 3) * 8;
    int grow0, grow1;
    if constexpr (MODE < 2) {
        grow0 = r0 + ar0; grow1 = r0 + ar1;
    } else {
        const int* bk = buckets + e * N_TOK;
        int p0 = r0 + ar0, p1 = r0 + ar1;
        int e0v = bk[p0 < rows ? p0 : 0];
        int e1v = bk[p1 < rows ? p1 : 0];
        grow0 = (MODE == 2) ? (e0v >> 1) : e0v;
        grow1 = (MODE == 2) ? (e1v >> 1) : e1v;
    }
    const unsigned short* aptr0 = Asrc + (size_t)grow0 * C_DIM + acol;
    const unsigned short* aptr1 = Asrc + (size_t)grow1 * C_DIM + acol;
    const unsigned short* bptr0 = Bmat + (size_t)(c0 + ar0) * C_DIM + acol;
    const unsigned short* bptr1 = Bmat + (size_t)(c0 + ar1) * C_DIM + acol;

    char* ldsA = (char*)&As[0];
    char* ldsB = (char*)&Bs[0];

    f32x4 acc[4][4];
    #pragma unroll
    for (int i = 0; i < 4; i++)
        #pragma unroll
        for (int j = 0; j < 4; j++) acc[i][j] = (f32x4){0.f, 0.f, 0.f, 0.f};

    for (int kt = 0; kt < C_DIM / 32; ++kt) {
        if (kt) __syncthreads();
        const int ko = kt * 32;
        GLOAD_LDS(aptr0 + ko, ldsA + t * 16);
        GLOAD_LDS(aptr1 + ko, ldsA + 4096 + t * 16);
        GLOAD_LDS(bptr0 + ko, ldsB + t * 16);
        GLOAD_LDS(bptr1 + ko, ldsB + 4096 + t * 16);
        __syncthreads();

        short8 af[4], bfr[4];
        #pragma unroll
        for (int i = 0; i < 4; i++)
            af[i] = *reinterpret_cast<const short8*>(&As[(size_t)(wr + i * 16 + (lane & 15)) * 32 + (lane >> 4) * 8]);
        #pragma unroll
        for (int j = 0; j < 4; j++)
            bfr[j] = *reinterpret_cast<const short8*>(&Bs[(size_t)(wc + j * 16 + (lane & 15)) * 32 + (lane >> 4) * 8]);
        #pragma unroll
        for (int i = 0; i < 4; i++)
            #pragma unroll
            for (int j = 0; j < 4; j++)
                acc[i][j] = __builtin_amdgcn_mfma_f32_16x16x32_bf16(
                    __builtin_bit_cast(bf16x8, af[i]), __builtin_bit_cast(bf16x8, bfr[j]), acc[i][j], 0, 0, 0);
    }

    const int fr = lane & 15;
    const int fq = lane >> 4;
    if constexpr (MODE == 0) {
        unsigned short* Hd = (unsigned short*)dst;
        #pragma unroll
        for (int i = 0; i < 4; i++)
            #pragma unroll
            for (int rr = 0; rr < 4; rr++) {
                int n = r0 + wr + i * 16 + fq * 4 + rr;
                size_t base = (size_t)n * C_DIM;
                #pragma unroll
                for (int j = 0; j < 4; j++) {
                    int col = c0 + wc + j * 16 + fr;
                    float v = acc[i][j][rr];
                    float rl = v > 0.f ? v : 0.f;
                    Hd[base + col] = f2bf(rl * rl);
                }
            }
    } else if constexpr (MODE == 1) {
        float* od = (float*)dst;
        #pragma unroll
        for (int i = 0; i < 4; i++)
            #pragma unroll
            for (int rr = 0; rr < 4; rr++) {
                int n = r0 + wr + i * 16 + fq * 4 + rr;
                size_t base = (size_t)n * C_DIM;
                #pragma unroll
                for (int j = 0; j < 4; j++) {
                    int col = c0 + wc + j * 16 + fr;
                    od[base + col] = acc[i][j][rr];
                }
            }
    } else {
        const int* bk = buckets + e * N_TOK;
        #pragma unroll
        for (int i = 0; i < 4; i++)
            #pragma unroll
            for (int rr = 0; rr < 4; rr++) {
                int pos = r0 + wr + i * 16 + fq * 4 + rr;
                if (pos < rows) {
                    int ent = bk[pos];
                    size_t base = (size_t)ent * C_DIM;
                    #pragma unroll
                    for (int j = 0; j < 4; j++) {
                        int col = c0 + wc + j * 16 + fr;
                        float v = acc[i][j][rr];
                        if (MODE == 2) {
                            float rl = v > 0.f ? v : 0.f;
                            ((unsigned short*)dst)[base + col] = f2bf(rl * rl);
                        } else {
                            ((unsigned short*)dst)[base + col] = f2bf(v);
                        }
                    }
                }
            }
    }
}

// ---------------- combine: out += w0*Y[n,0] + w1*Y[n,1] ----------------
__global__ void combine_kernel(float* __restrict__ out, const unsigned short* __restrict__ Y,
                               const float* __restrict__ tw) {
    int idx = blockIdx.x * blockDim.x + threadIdx.x;
    const int per_row = C_DIM / 4;
    if (idx >= N_TOK * per_row) return;
    int n = idx / per_row;
    int c = (idx % per_row) * 4;
    float w0 = tw[n * 2], w1 = tw[n * 2 + 1];
    const ushort4 a = *reinterpret_cast<const ushort4*>(Y + (size_t)(n * 2) * C_DIM + c);
    const ushort4 b = *reinterpret_cast<const ushort4*>(Y + (size_t)(n * 2 + 1) * C_DIM + c);
    float4* op = reinterpret_cast<float4*>(out + (size_t)n * C_DIM + c);
    float4 o = *op;
    o.x += w0 * bf2f(a.x) + w1 * bf2f(b.x);
    o.y += w0 * bf2f(a.y) + w1 * bf2f(b.y);
    o.z += w0 * bf2f(a.z) + w1 * bf2f(b.z);
    o.w += w0 * bf2f(a.w) + w1 * bf2f(b.w);
    *op = o;
}

extern "C" void kernel_launch(void* const* d_in, const int* in_sizes, int n_in,
                              void* d_out, int out_size, void* d_ws, size_t ws_size,
                              hipStream_t stream) {
    const float* x   = (const float*)d_in[0];
    const float* wfc = (const float*)d_in[1];
    const float* wpj = (const float*)d_in[2];
    const float* w1  = (const float*)d_in[3];
    const float* w2  = (const float*)d_in[4];
    const float* rw  = (const float*)d_in[5];
    const float* bias= (const float*)d_in[6];
    float* out = (float*)d_out;

    char* ws = (char*)d_ws;
    size_t off = 0;
    auto alloc = [&](size_t bytes) { void* p = ws + off; off += (bytes + 255) & ~(size_t)255; return p; };
    unsigned short* xb   = (unsigned short*)alloc((size_t)N_TOK * C_DIM * 2);
    unsigned short* Wt   = (unsigned short*)alloc((size_t)18 * C_DIM * C_DIM * 2);
    unsigned short* H    = (unsigned short*)alloc((size_t)N_TOK * 2 * C_DIM * 2);
    unsigned short* Y    = (unsigned short*)alloc((size_t)N_TOK * 2 * C_DIM * 2);
    float* topk_w        = (float*)alloc((size_t)N_TOK * 2 * 4);
    int* counts          = (int*)alloc(256);
    int* buckets         = (int*)alloc((size_t)E_NUM * N_TOK * 4);

    hipMemsetAsync(counts, 0, E_NUM * sizeof(int), stream);

    convert_x_kernel<<<(N_TOK * C_DIM / 4 + 255) / 256, 256, 0, stream>>>(x, xb, N_TOK * C_DIM / 4);
    wtrans_kernel<<<dim3(24, 24, 18), dim3(32, 8), 0, stream>>>(wfc, wpj, w1, w2, Wt);
    router_kernel<<<N_TOK / 4, 256, 0, stream>>>(x, rw, bias, topk_w, counts, buckets);

    // shared expert
    gemm_kernel<0><<<dim3(64, 6), 256, 0, stream>>>(xb, Wt, H, nullptr, nullptr);
    gemm_kernel<1><<<dim3(64, 6), 256, 0, stream>>>(H, Wt, out, nullptr, nullptr);
    // routed experts (all experts in one launch; early-exit past counts)
    gemm_kernel<2><<<dim3(64, 6, E_NUM), 256, 0, stream>>>(xb, Wt, H, counts, buckets);
    gemm_kernel<3><<<dim3(64, 6, E_NUM), 256, 0, stream>>>(H, Wt, Y, counts, buckets);

    combine_kernel<<<(N_TOK * (C_DIM / 4) + 255) / 256, 256, 0, stream>>>(out, Y, topk_w);
}

// Round 2
// 204.934 us; speedup vs baseline: 1.8469x; 1.8469x over previous
//
#include <hip/hip_runtime.h>
#include <stdint.h>

#define N_TOK 8192
#define C_DIM 768
#define E_NUM 8

typedef short short8 __attribute__((ext_vector_type(8)));
typedef __bf16 bf16x8 __attribute__((ext_vector_type(8)));
typedef float f32x4 __attribute__((ext_vector_type(4)));

static __device__ __forceinline__ unsigned short f2bf(float f) {
    unsigned u = __float_as_uint(f);
    unsigned r = u + 0x7FFFu + ((u >> 16) & 1u);
    return (unsigned short)(r >> 16);
}
static __device__ __forceinline__ float bf2f(unsigned short h) {
    return __uint_as_float(((unsigned)h) << 16);
}

// ---------------- convert x: fp32 -> bf16 ----------------
__global__ void convert_x_kernel(const float* __restrict__ x, unsigned short* __restrict__ xb, int n4) {
    int i = blockIdx.x * blockDim.x + threadIdx.x;
    if (i >= n4) return;
    const float4 v = *reinterpret_cast<const float4*>(x + (size_t)i * 4);
    ushort4 o;
    o.x = f2bf(v.x); o.y = f2bf(v.y); o.z = f2bf(v.z); o.w = f2bf(v.w);
    *reinterpret_cast<ushort4*>(xb + (size_t)i * 4) = o;
}

// ------------- transpose+convert weights: Wt[m][o][i] = W[m][i][o], bf16 -------------
// m: 0=w_fc_sh, 1=w_proj_sh, 2..9=w1[e], 10..17=w2[e]
__global__ void wtrans_kernel(const float* __restrict__ wfc, const float* __restrict__ wpj,
                              const float* __restrict__ w1, const float* __restrict__ w2,
                              unsigned short* __restrict__ Wt) {
    __shared__ float tile[32][33];
    const int m = blockIdx.z;
    const float* src = (m == 0) ? wfc : (m == 1) ? wpj
                     : (m < 10) ? (w1 + (size_t)(m - 2) * C_DIM * C_DIM)
                                : (w2 + (size_t)(m - 10) * C_DIM * C_DIM);
    const int i0 = blockIdx.y * 32;   // input-dim block
    const int o0 = blockIdx.x * 32;   // output-dim block
    #pragma unroll
    for (int rr = 0; rr < 32; rr += 8)
        tile[threadIdx.y + rr][threadIdx.x] = src[(size_t)(i0 + threadIdx.y + rr) * C_DIM + o0 + threadIdx.x];
    __syncthreads();
    unsigned short* dst = Wt + (size_t)m * C_DIM * C_DIM;
    #pragma unroll
    for (int rr = 0; rr < 32; rr += 8) {
        int o = o0 + threadIdx.y + rr;
        dst[(size_t)o * C_DIM + i0 + threadIdx.x] = f2bf(tile[threadIdx.x][threadIdx.y + rr]);
    }
}

// ---------------- router pass 1: fp32 logits, sigmoid, top-2 (NO atomics) ----------------
__global__ void router_kernel(const float* __restrict__ x, const float* __restrict__ rw,
                              const float* __restrict__ bias,
                              float* __restrict__ topk_w, int* __restrict__ eids) {
    const int wave = threadIdx.x >> 6;
    const int lane = threadIdx.x & 63;
    const int n = blockIdx.x * 4 + wave;
    const float* xp = x + (size_t)n * C_DIM + lane * 12;
    float xv[12];
    #pragma unroll
    for (int j = 0; j < 12; j++) xv[j] = xp[j];
    float acc[E_NUM];
    #pragma unroll
    for (int e = 0; e < E_NUM; e++) acc[e] = 0.f;
    #pragma unroll
    for (int e = 0; e < E_NUM; e++) {
        const float* wp = rw + (size_t)e * C_DIM + lane * 12;
        #pragma unroll
        for (int j = 0; j < 12; j++) acc[e] += xv[j] * wp[j];
    }
    #pragma unroll
    for (int e = 0; e < E_NUM; e++) {
        #pragma unroll
        for (int off = 32; off > 0; off >>= 1) acc[e] += __shfl_xor(acc[e], off, 64);
    }
    if (lane == 0) {
        float sc[E_NUM];
        #pragma unroll
        for (int e = 0; e < E_NUM; e++) sc[e] = 1.f / (1.f + expf(-acc[e]));
        int e0 = 0; float best = -1e30f;
        #pragma unroll
        for (int e = 0; e < E_NUM; e++) { float v = sc[e] + bias[e]; if (v > best) { best = v; e0 = e; } }
        int e1 = -1; float best1 = -1e30f;
        #pragma unroll
        for (int e = 0; e < E_NUM; e++) { if (e == e0) continue; float v = sc[e] + bias[e]; if (v > best1) { best1 = v; e1 = e; } }
        float w0 = sc[e0], w1 = sc[e1];
        float s = w0 + w1 + 1e-20f;
        w0 /= s; w1 /= s;
        topk_w[n * 2] = w0; topk_w[n * 2 + 1] = w1;
        eids[n * 2] = e0; eids[n * 2 + 1] = e1;
    }
}

// ---------------- router pass 2: per-expert compaction (deterministic, no atomics) ----------------
__global__ __launch_bounds__(1024) void bucketize_kernel(const int* __restrict__ eids,
                                                         int* __restrict__ counts,
                                                         int* __restrict__ buckets) {
    const int e = blockIdx.x;
    const int t = threadIdx.x;
    const int wv = t >> 6, lane = t & 63;
    __shared__ int wave_tot[16];
    int running = 0;
    for (int start = 0; start < 2 * N_TOK; start += 1024) {
        const int i = start + t;
        const int f = (eids[i] == e) ? 1 : 0;
        unsigned long long mask = __ballot(f);
        int pre = __popcll(mask & ((1ull << lane) - 1ull));
        if (lane == 0) wave_tot[wv] = __popcll(mask);
        __syncthreads();
        int wbase = 0, tot = 0;
        #pragma unroll
        for (int j = 0; j < 16; j++) { int c = wave_tot[j]; tot += c; if (j < wv) wbase += c; }
        if (f) buckets[e * N_TOK + running + wbase + pre] = i;
        running += tot;
        __syncthreads();
    }
    if (t == 0) counts[e] = running;
}

// ---------------- bf16 MFMA GEMM, 128x128 tile, BK=32, 4 waves ----------------
// MODE 0: shared fc:   A=xb rows direct,   epi relu^2 -> H[n]        (bf16)
// MODE 1: shared proj: A=H rows direct,    epi write  -> out[n]      (fp32)
// MODE 2: expert fc:   A=xb gathered,      epi relu^2 -> H[entry]    (bf16)
// MODE 3: expert proj: A=H gathered,       epi write  -> Y[entry]    (bf16)
#define GLOAD_LDS(g, l) __builtin_amdgcn_global_load_lds((const __attribute__((address_space(1))) void*)(g), (__attribute__((address_space(3))) void*)(l), 16, 0, 0)

template <int MODE>
__global__ __launch_bounds__(256) void gemm_kernel(const unsigned short* __restrict__ Asrc,
                                                   const unsigned short* __restrict__ WtAll,
                                                   void* __restrict__ dst,
                                                   const int* __restrict__ counts,
                                                   const int* __restrict__ buckets) {
    const int e = (MODE >= 2) ? blockIdx.z : 0;
    int rows;
    if constexpr (MODE < 2) rows = N_TOK; else rows = counts[e];
    const int r0 = blockIdx.x * 128;
    if (r0 >= rows) return;
    const int c0 = blockIdx.y * 128;

    __shared__ __align__(16) unsigned short As[128 * 32];
    __shared__ __align__(16) unsigned short Bs[128 * 32];

    const int t = threadIdx.x;
    const int lane = t & 63;
    const int wv = t >> 6;
    const int wr = (wv >> 1) * 64;
    const int wc = (wv & 1) * 64;

    const int widx = (MODE == 0) ? 0 : (MODE == 1) ? 1 : (MODE == 2) ? (2 + e) : (10 + e);
    const unsigned short* Bmat = WtAll + (size_t)widx * C_DIM * C_DIM;

    // staging row map (2 rows per thread per tile)
    const int ar0 = t >> 2;
    const int ar1 = 64 + (t >> 2);
    const int acol = (t & 3) * 8;
    int grow0, grow1;
    if constexpr (MODE < 2) {
        grow0 = r0 + ar0; grow1 = r0 + ar1;
    } else {
        const int* bk = buckets + e * N_TOK;
        int p0 = r0 + ar0, p1 = r0 + ar1;
        int e0v = bk[p0 < rows ? p0 : 0];
        int e1v = bk[p1 < rows ? p1 : 0];
        grow0 = (MODE == 2) ? (e0v >> 1) : e0v;
        grow1 = (MODE == 2) ? (e1v >> 1) : e1v;
    }
    const unsigned short* aptr0 = Asrc + (size_t)grow0 * C_DIM + acol;
    const unsigned short* aptr1 = Asrc + (size_t)grow1 * C_DIM + acol;
    const unsigned short* bptr0 = Bmat + (size_t)(c0 + ar0) * C_DIM + acol;
    const unsigned short* bptr1 = Bmat + (size_t)(c0 + ar1) * C_DIM + acol;

    char* ldsA = (char*)&As[0];
    char* ldsB = (char*)&Bs[0];

    f32x4 acc[4][4];
    #pragma unroll
    for (int i = 0; i < 4; i++)
        #pragma unroll
        for (int j = 0; j < 4; j++) acc[i][j] = (f32x4){0.f, 0.f, 0.f, 0.f};

    for (int kt = 0; kt < C_DIM / 32; ++kt) {
        if (kt) __syncthreads();
        const int ko = kt * 32;
        GLOAD_LDS(aptr0 + ko, ldsA + t * 16);
        GLOAD_LDS(aptr1 + ko, ldsA + 4096 + t * 16);
        GLOAD_LDS(bptr0 + ko, ldsB + t * 16);
        GLOAD_LDS(bptr1 + ko, ldsB + 4096 + t * 16);
        __syncthreads();

        short8 af[4], bfr[4];
        #pragma unroll
        for (int i = 0; i < 4; i++)
            af[i] = *reinterpret_cast<const short8*>(&As[(size_t)(wr + i * 16 + (lane & 15)) * 32 + (lane >> 4) * 8]);
        #pragma unroll
        for (int j = 0; j < 4; j++)
            bfr[j] = *reinterpret_cast<const short8*>(&Bs[(size_t)(wc + j * 16 + (lane & 15)) * 32 + (lane >> 4) * 8]);
        #pragma unroll
        for (int i = 0; i < 4; i++)
            #pragma unroll
            for (int j = 0; j < 4; j++)
                acc[i][j] = __builtin_amdgcn_mfma_f32_16x16x32_bf16(
                    __builtin_bit_cast(bf16x8, af[i]), __builtin_bit_cast(bf16x8, bfr[j]), acc[i][j], 0, 0, 0);
    }

    const int fr = lane & 15;
    const int fq = lane >> 4;
    if constexpr (MODE == 0) {
        unsigned short* Hd = (unsigned short*)dst;
        #pragma unroll
        for (int i = 0; i < 4; i++)
            #pragma unroll
            for (int rr = 0; rr < 4; rr++) {
                int n = r0 + wr + i * 16 + fq * 4 + rr;
                size_t base = (size_t)n * C_DIM;
                #pragma unroll
                for (int j = 0; j < 4; j++) {
                    int col = c0 + wc + j * 16 + fr;
                    float v = acc[i][j][rr];
                    float rl = v > 0.f ? v : 0.f;
                    Hd[base + col] = f2bf(rl * rl);
                }
            }
    } else if constexpr (MODE == 1) {
        float* od = (float*)dst;
        #pragma unroll
        for (int i = 0; i < 4; i++)
            #pragma unroll
            for (int rr = 0; rr < 4; rr++) {
                int n = r0 + wr + i * 16 + fq * 4 + rr;
                size_t base = (size_t)n * C_DIM;
                #pragma unroll
                for (int j = 0; j < 4; j++) {
                    int col = c0 + wc + j * 16 + fr;
                    od[base + col] = acc[i][j][rr];
                }
            }
    } else {
        const int* bk = buckets + e * N_TOK;
        #pragma unroll
        for (int i = 0; i < 4; i++)
            #pragma unroll
            for (int rr = 0; rr < 4; rr++) {
                int pos = r0 + wr + i * 16 + fq * 4 + rr;
                if (pos < rows) {
                    int ent = bk[pos];
                    size_t base = (size_t)ent * C_DIM;
                    #pragma unroll
                    for (int j = 0; j < 4; j++) {
                        int col = c0 + wc + j * 16 + fr;
                        float v = acc[i][j][rr];
                        if (MODE == 2) {
                            float rl = v > 0.f ? v : 0.f;
                            ((unsigned short*)dst)[base + col] = f2bf(rl * rl);
                        } else {
                            ((unsigned short*)dst)[base + col] = f2bf(v);
                        }
                    }
                }
            }
    }
}

// ---------------- combine: out += w0*Y[n,0] + w1*Y[n,1] ----------------
__global__ void combine_kernel(float* __restrict__ out, const unsigned short* __restrict__ Y,
                               const float* __restrict__ tw) {
    int idx = blockIdx.x * blockDim.x + threadIdx.x;
    const int per_row = C_DIM / 4;
    if (idx >= N_TOK * per_row) return;
    int n = idx / per_row;
    int c = (idx % per_row) * 4;
    float w0 = tw[n * 2], w1 = tw[n * 2 + 1];
    const ushort4 a = *reinterpret_cast<const ushort4*>(Y + (size_t)(n * 2) * C_DIM + c);
    const ushort4 b = *reinterpret_cast<const ushort4*>(Y + (size_t)(n * 2 + 1) * C_DIM + c);
    float4* op = reinterpret_cast<float4*>(out + (size_t)n * C_DIM + c);
    float4 o = *op;
    o.x += w0 * bf2f(a.x) + w1 * bf2f(b.x);
    o.y += w0 * bf2f(a.y) + w1 * bf2f(b.y);
    o.z += w0 * bf2f(a.z) + w1 * bf2f(b.z);
    o.w += w0 * bf2f(a.w) + w1 * bf2f(b.w);
    *op = o;
}

extern "C" void kernel_launch(void* const* d_in, const int* in_sizes, int n_in,
                              void* d_out, int out_size, void* d_ws, size_t ws_size,
                              hipStream_t stream) {
    const float* x   = (const float*)d_in[0];
    const float* wfc = (const float*)d_in[1];
    const float* wpj = (const float*)d_in[2];
    const float* w1  = (const float*)d_in[3];
    const float* w2  = (const float*)d_in[4];
    const float* rw  = (const float*)d_in[5];
    const float* bias= (const float*)d_in[6];
    float* out = (float*)d_out;

    char* ws = (char*)d_ws;
    size_t off = 0;
    auto alloc = [&](size_t bytes) { void* p = ws + off; off += (bytes + 255) & ~(size_t)255; return p; };
    unsigned short* xb   = (unsigned short*)alloc((size_t)N_TOK * C_DIM * 2);
    unsigned short* Wt   = (unsigned short*)alloc((size_t)18 * C_DIM * C_DIM * 2);
    unsigned short* H    = (unsigned short*)alloc((size_t)N_TOK * 2 * C_DIM * 2);
    unsigned short* Y    = (unsigned short*)alloc((size_t)N_TOK * 2 * C_DIM * 2);
    float* topk_w        = (float*)alloc((size_t)N_TOK * 2 * 4);
    int* counts          = (int*)alloc(256);
    int* buckets         = (int*)alloc((size_t)E_NUM * N_TOK * 4);
    int* eids            = (int*)alloc((size_t)2 * N_TOK * 4);

    convert_x_kernel<<<(N_TOK * C_DIM / 4 + 255) / 256, 256, 0, stream>>>(x, xb, N_TOK * C_DIM / 4);
    wtrans_kernel<<<dim3(24, 24, 18), dim3(32, 8), 0, stream>>>(wfc, wpj, w1, w2, Wt);
    router_kernel<<<N_TOK / 4, 256, 0, stream>>>(x, rw, bias, topk_w, eids);
    bucketize_kernel<<<E_NUM, 1024, 0, stream>>>(eids, counts, buckets);

    // shared expert
    gemm_kernel<0><<<dim3(64, 6), 256, 0, stream>>>(xb, Wt, H, nullptr, nullptr);
    gemm_kernel<1><<<dim3(64, 6), 256, 0, stream>>>(H, Wt, out, nullptr, nullptr);
    // routed experts (all experts in one launch; early-exit past counts)
    gemm_kernel<2><<<dim3(64, 6, E_NUM), 256, 0, stream>>>(xb, Wt, H, counts, buckets);
    gemm_kernel<3><<<dim3(64, 6, E_NUM), 256, 0, stream>>>(H, Wt, Y, counts, buckets);

    combine_kernel<<<(N_TOK * (C_DIM / 4) + 255) / 256, 256, 0, stream>>>(out, Y, topk_w);
}

// Round 3
// 202.026 us; speedup vs baseline: 1.8735x; 1.0144x over previous
//
#include <hip/hip_runtime.h>
#include <stdint.h>

#define N_TOK 8192
#define C_DIM 768
#define E_NUM 8

typedef short short8 __attribute__((ext_vector_type(8)));
typedef __bf16 bf16x8 __attribute__((ext_vector_type(8)));
typedef float f32x4 __attribute__((ext_vector_type(4)));

static __device__ __forceinline__ unsigned short f2bf(float f) {
    unsigned u = __float_as_uint(f);
    unsigned r = u + 0x7FFFu + ((u >> 16) & 1u);
    return (unsigned short)(r >> 16);
}
static __device__ __forceinline__ float bf2f(unsigned short h) {
    return __uint_as_float(((unsigned)h) << 16);
}

// ---------------- convert x: fp32 -> bf16 ----------------
__global__ void convert_x_kernel(const float* __restrict__ x, unsigned short* __restrict__ xb, int n4) {
    int i = blockIdx.x * blockDim.x + threadIdx.x;
    if (i >= n4) return;
    const float4 v = *reinterpret_cast<const float4*>(x + (size_t)i * 4);
    ushort4 o;
    o.x = f2bf(v.x); o.y = f2bf(v.y); o.z = f2bf(v.z); o.w = f2bf(v.w);
    *reinterpret_cast<ushort4*>(xb + (size_t)i * 4) = o;
}

// ------------- transpose+convert weights: Wt[m][o][i] = W[m][i][o], bf16 -------------
__global__ void wtrans_kernel(const float* __restrict__ wfc, const float* __restrict__ wpj,
                              const float* __restrict__ w1, const float* __restrict__ w2,
                              unsigned short* __restrict__ Wt) {
    __shared__ float tile[32][33];
    const int m = blockIdx.z;
    const float* src = (m == 0) ? wfc : (m == 1) ? wpj
                     : (m < 10) ? (w1 + (size_t)(m - 2) * C_DIM * C_DIM)
                                : (w2 + (size_t)(m - 10) * C_DIM * C_DIM);
    const int i0 = blockIdx.y * 32;
    const int o0 = blockIdx.x * 32;
    #pragma unroll
    for (int rr = 0; rr < 32; rr += 8)
        tile[threadIdx.y + rr][threadIdx.x] = src[(size_t)(i0 + threadIdx.y + rr) * C_DIM + o0 + threadIdx.x];
    __syncthreads();
    unsigned short* dst = Wt + (size_t)m * C_DIM * C_DIM;
    #pragma unroll
    for (int rr = 0; rr < 32; rr += 8) {
        int o = o0 + threadIdx.y + rr;
        dst[(size_t)o * C_DIM + i0 + threadIdx.x] = f2bf(tile[threadIdx.x][threadIdx.y + rr]);
    }
}

// ---------------- router pass 1: fp32 logits, sigmoid, top-2 (no atomics) ----------------
__global__ void router_kernel(const float* __restrict__ x, const float* __restrict__ rw,
                              const float* __restrict__ bias,
                              float* __restrict__ topk_w, int* __restrict__ eids) {
    const int wave = threadIdx.x >> 6;
    const int lane = threadIdx.x & 63;
    const int n = blockIdx.x * 4 + wave;
    const float* xp = x + (size_t)n * C_DIM + lane * 12;
    float xv[12];
    #pragma unroll
    for (int j = 0; j < 12; j++) xv[j] = xp[j];
    float acc[E_NUM];
    #pragma unroll
    for (int e = 0; e < E_NUM; e++) acc[e] = 0.f;
    #pragma unroll
    for (int e = 0; e < E_NUM; e++) {
        const float* wp = rw + (size_t)e * C_DIM + lane * 12;
        #pragma unroll
        for (int j = 0; j < 12; j++) acc[e] += xv[j] * wp[j];
    }
    #pragma unroll
    for (int e = 0; e < E_NUM; e++) {
        #pragma unroll
        for (int off = 32; off > 0; off >>= 1) acc[e] += __shfl_xor(acc[e], off, 64);
    }
    if (lane == 0) {
        float sc[E_NUM];
        #pragma unroll
        for (int e = 0; e < E_NUM; e++) sc[e] = 1.f / (1.f + expf(-acc[e]));
        int e0 = 0; float best = -1e30f;
        #pragma unroll
        for (int e = 0; e < E_NUM; e++) { float v = sc[e] + bias[e]; if (v > best) { best = v; e0 = e; } }
        int e1 = -1; float best1 = -1e30f;
        #pragma unroll
        for (int e = 0; e < E_NUM; e++) { if (e == e0) continue; float v = sc[e] + bias[e]; if (v > best1) { best1 = v; e1 = e; } }
        float w0 = sc[e0], w1 = sc[e1];
        float s = w0 + w1 + 1e-20f;
        w0 /= s; w1 /= s;
        topk_w[n * 2] = w0; topk_w[n * 2 + 1] = w1;
        eids[n * 2] = e0; eids[n * 2 + 1] = e1;
    }
}

// ---------------- router pass 2: per-expert compaction (deterministic) ----------------
__global__ __launch_bounds__(1024) void bucketize_kernel(const int* __restrict__ eids,
                                                         int* __restrict__ counts,
                                                         int* __restrict__ buckets) {
    const int e = blockIdx.x;
    const int t = threadIdx.x;
    const int wv = t >> 6, lane = t & 63;
    __shared__ int wave_tot[16];
    int running = 0;
    for (int start = 0; start < 2 * N_TOK; start += 1024) {
        const int i = start + t;
        const int f = (eids[i] == e) ? 1 : 0;
        unsigned long long mask = __ballot(f);
        int pre = __popcll(mask & ((1ull << lane) - 1ull));
        if (lane == 0) wave_tot[wv] = __popcll(mask);
        __syncthreads();
        int wbase = 0, tot = 0;
        #pragma unroll
        for (int j = 0; j < 16; j++) { int c = wave_tot[j]; tot += c; if (j < wv) wbase += c; }
        if (f) buckets[e * N_TOK + running + wbase + pre] = i;
        running += tot;
        __syncthreads();
    }
    if (t == 0) counts[e] = running;
}

// ---------------- merged bf16 MFMA GEMM: z in [0,8]; z<8 = expert (gathered), z==8 = shared ----
// PHASE 0 (fc):   A = xb (z=8 direct; z<8 gather token=ent>>1); epi relu^2 -> Hsh[n] / H[ent]
// PHASE 1 (proj): A = Hsh (z=8) / H gathered by ent (z<8);      epi -> out[n] fp32 / Y[ent] bf16
// LDS swizzle (bank-conflict-free ds_read_b128): LDS slot (row r, q') holds global col-slot
// q = q' ^ ((r>>1)&3).  Staged via pre-swizzled global source (global_load_lds dest stays linear).
#define GLOAD_LDS(g, l) __builtin_amdgcn_global_load_lds((const __attribute__((address_space(1))) void*)(g), (__attribute__((address_space(3))) void*)(l), 16, 0, 0)

template <int PHASE>
__global__ __launch_bounds__(256) void gemm_all_kernel(const unsigned short* __restrict__ Adir,
                                                       const unsigned short* __restrict__ Agat,
                                                       const unsigned short* __restrict__ WtAll,
                                                       void* __restrict__ dstDir,
                                                       unsigned short* __restrict__ dstGat,
                                                       const int* __restrict__ counts,
                                                       const int* __restrict__ buckets) {
    const int z = blockIdx.z;
    const bool shared_blk = (z == E_NUM);
    const int rows = shared_blk ? N_TOK : counts[z];
    const int r0 = blockIdx.x * 128;
    if (r0 >= rows) return;
    const int c0 = blockIdx.y * 128;

    __shared__ __align__(16) unsigned short As[128 * 32];
    __shared__ __align__(16) unsigned short Bs[128 * 32];

    const int t = threadIdx.x;
    const int lane = t & 63;
    const int wv = t >> 6;
    const int wr = (wv >> 1) * 64;
    const int wc = (wv & 1) * 64;

    const int widx = shared_blk ? (PHASE == 0 ? 0 : 1) : (PHASE == 0 ? 2 + z : 10 + z);
    const unsigned short* Bmat = WtAll + (size_t)widx * C_DIM * C_DIM;

    // staging: thread t -> LDS rows (t>>2, 64+(t>>2)), LDS col-slot q'=t&3 (linear dest),
    // global col-slot pre-swizzled: q = (t&3) ^ ((t>>3)&3)   [(row>>1)&3 == (t>>3)&3 for both rows]
    const int ar0 = t >> 2;
    const int ar1 = 64 + (t >> 2);
    const int acol = (((t & 3) ^ ((t >> 3) & 3)) * 8);
    int grow0, grow1;
    const unsigned short* Asrc;
    if (shared_blk) {
        Asrc = Adir;
        grow0 = r0 + ar0; grow1 = r0 + ar1;
    } else {
        Asrc = Agat;
        const int* bk = buckets + z * N_TOK;
        int p0 = r0 + ar0, p1 = r0 + ar1;
        int e0v = bk[p0 < rows ? p0 : 0];
        int e1v = bk[p1 < rows ? p1 : 0];
        grow0 = (PHASE == 0) ? (e0v >> 1) : e0v;
        grow1 = (PHASE == 0) ? (e1v >> 1) : e1v;
    }
    const unsigned short* aptr0 = Asrc + (size_t)grow0 * C_DIM + acol;
    const unsigned short* aptr1 = Asrc + (size_t)grow1 * C_DIM + acol;
    const unsigned short* bptr0 = Bmat + (size_t)(c0 + ar0) * C_DIM + acol;
    const unsigned short* bptr1 = Bmat + (size_t)(c0 + ar1) * C_DIM + acol;

    char* ldsA = (char*)&As[0];
    char* ldsB = (char*)&Bs[0];

    f32x4 acc[4][4];
    #pragma unroll
    for (int i = 0; i < 4; i++)
        #pragma unroll
        for (int j = 0; j < 4; j++) acc[i][j] = (f32x4){0.f, 0.f, 0.f, 0.f};

    // fragment-read LDS col-slot: q' = (lane>>4) ^ ((r>>1)&3), (r>>1)&3 == (lane>>1)&3
    const int qr = (((lane >> 4) ^ ((lane >> 1) & 3)) * 8);

    for (int kt = 0; kt < C_DIM / 32; ++kt) {
        if (kt) __syncthreads();
        const int ko = kt * 32;
        GLOAD_LDS(aptr0 + ko, ldsA + t * 16);
        GLOAD_LDS(aptr1 + ko, ldsA + 4096 + t * 16);
        GLOAD_LDS(bptr0 + ko, ldsB + t * 16);
        GLOAD_LDS(bptr1 + ko, ldsB + 4096 + t * 16);
        __syncthreads();

        short8 af[4], bfr[4];
        #pragma unroll
        for (int i = 0; i < 4; i++)
            af[i] = *reinterpret_cast<const short8*>(&As[(size_t)(wr + i * 16 + (lane & 15)) * 32 + qr]);
        #pragma unroll
        for (int j = 0; j < 4; j++)
            bfr[j] = *reinterpret_cast<const short8*>(&Bs[(size_t)(wc + j * 16 + (lane & 15)) * 32 + qr]);
        #pragma unroll
        for (int i = 0; i < 4; i++)
            #pragma unroll
            for (int j = 0; j < 4; j++)
                acc[i][j] = __builtin_amdgcn_mfma_f32_16x16x32_bf16(
                    __builtin_bit_cast(bf16x8, af[i]), __builtin_bit_cast(bf16x8, bfr[j]), acc[i][j], 0, 0, 0);
    }

    const int fr = lane & 15;
    const int fq = lane >> 4;
    if (shared_blk) {
        if constexpr (PHASE == 0) {
            unsigned short* Hd = (unsigned short*)dstDir;
            #pragma unroll
            for (int i = 0; i < 4; i++)
                #pragma unroll
                for (int rr = 0; rr < 4; rr++) {
                    int n = r0 + wr + i * 16 + fq * 4 + rr;
                    size_t base = (size_t)n * C_DIM;
                    #pragma unroll
                    for (int j = 0; j < 4; j++) {
                        int col = c0 + wc + j * 16 + fr;
                        float v = acc[i][j][rr];
                        float rl = v > 0.f ? v : 0.f;
                        Hd[base + col] = f2bf(rl * rl);
                    }
                }
        } else {
            float* od = (float*)dstDir;
            #pragma unroll
            for (int i = 0; i < 4; i++)
                #pragma unroll
                for (int rr = 0; rr < 4; rr++) {
                    int n = r0 + wr + i * 16 + fq * 4 + rr;
                    size_t base = (size_t)n * C_DIM;
                    #pragma unroll
                    for (int j = 0; j < 4; j++) {
                        int col = c0 + wc + j * 16 + fr;
                        od[base + col] = acc[i][j][rr];
                    }
                }
        }
    } else {
        const int* bk = buckets + z * N_TOK;
        #pragma unroll
        for (int i = 0; i < 4; i++)
            #pragma unroll
            for (int rr = 0; rr < 4; rr++) {
                int pos = r0 + wr + i * 16 + fq * 4 + rr;
                if (pos < rows) {
                    int ent = bk[pos];
                    size_t base = (size_t)ent * C_DIM;
                    #pragma unroll
                    for (int j = 0; j < 4; j++) {
                        int col = c0 + wc + j * 16 + fr;
                        float v = acc[i][j][rr];
                        if (PHASE == 0) {
                            float rl = v > 0.f ? v : 0.f;
                            dstGat[base + col] = f2bf(rl * rl);
                        } else {
                            dstGat[base + col] = f2bf(v);
                        }
                    }
                }
            }
    }
}

// ---------------- combine: out += w0*Y[n,0] + w1*Y[n,1] ----------------
__global__ void combine_kernel(float* __restrict__ out, const unsigned short* __restrict__ Y,
                               const float* __restrict__ tw) {
    int idx = blockIdx.x * blockDim.x + threadIdx.x;
    const int per_row = C_DIM / 4;
    if (idx >= N_TOK * per_row) return;
    int n = idx / per_row;
    int c = (idx % per_row) * 4;
    float w0 = tw[n * 2], w1 = tw[n * 2 + 1];
    const ushort4 a = *reinterpret_cast<const ushort4*>(Y + (size_t)(n * 2) * C_DIM + c);
    const ushort4 b = *reinterpret_cast<const ushort4*>(Y + (size_t)(n * 2 + 1) * C_DIM + c);
    float4* op = reinterpret_cast<float4*>(out + (size_t)n * C_DIM + c);
    float4 o = *op;
    o.x += w0 * bf2f(a.x) + w1 * bf2f(b.x);
    o.y += w0 * bf2f(a.y) + w1 * bf2f(b.y);
    o.z += w0 * bf2f(a.z) + w1 * bf2f(b.z);
    o.w += w0 * bf2f(a.w) + w1 * bf2f(b.w);
    *op = o;
}

extern "C" void kernel_launch(void* const* d_in, const int* in_sizes, int n_in,
                              void* d_out, int out_size, void* d_ws, size_t ws_size,
                              hipStream_t stream) {
    const float* x   = (const float*)d_in[0];
    const float* wfc = (const float*)d_in[1];
    const float* wpj = (const float*)d_in[2];
    const float* w1  = (const float*)d_in[3];
    const float* w2  = (const float*)d_in[4];
    const float* rw  = (const float*)d_in[5];
    const float* bias= (const float*)d_in[6];
    float* out = (float*)d_out;

    char* ws = (char*)d_ws;
    size_t off = 0;
    auto alloc = [&](size_t bytes) { void* p = ws + off; off += (bytes + 255) & ~(size_t)255; return p; };
    unsigned short* xb   = (unsigned short*)alloc((size_t)N_TOK * C_DIM * 2);
    unsigned short* Wt   = (unsigned short*)alloc((size_t)18 * C_DIM * C_DIM * 2);
    unsigned short* H    = (unsigned short*)alloc((size_t)N_TOK * 2 * C_DIM * 2);  // expert hidden, by entry id
    unsigned short* Hsh  = (unsigned short*)alloc((size_t)N_TOK * C_DIM * 2);      // shared hidden
    unsigned short* Y    = (unsigned short*)alloc((size_t)N_TOK * 2 * C_DIM * 2);  // expert out, by entry id
    float* topk_w        = (float*)alloc((size_t)N_TOK * 2 * 4);
    int* counts          = (int*)alloc(256);
    int* buckets         = (int*)alloc((size_t)E_NUM * N_TOK * 4);
    int* eids            = (int*)alloc((size_t)2 * N_TOK * 4);

    convert_x_kernel<<<(N_TOK * C_DIM / 4 + 255) / 256, 256, 0, stream>>>(x, xb, N_TOK * C_DIM / 4);
    wtrans_kernel<<<dim3(24, 24, 18), dim3(32, 8), 0, stream>>>(wfc, wpj, w1, w2, Wt);
    router_kernel<<<N_TOK / 4, 256, 0, stream>>>(x, rw, bias, topk_w, eids);
    bucketize_kernel<<<E_NUM, 1024, 0, stream>>>(eids, counts, buckets);

    // fc for shared (z=8) + all experts (z<8) in one launch
    gemm_all_kernel<0><<<dim3(64, 6, E_NUM + 1), 256, 0, stream>>>(xb, xb, Wt, Hsh, H, counts, buckets);
    // proj for shared + all experts in one launch
    gemm_all_kernel<1><<<dim3(64, 6, E_NUM + 1), 256, 0, stream>>>(Hsh, H, Wt, out, Y, counts, buckets);

    combine_kernel<<<(N_TOK * (C_DIM / 4) + 255) / 256, 256, 0, stream>>>(out, Y, topk_w);
}